// Round 10
// baseline (766.503 us; speedup 1.0000x reference)
//
#include <hip/hip_runtime.h>
#include <math.h>

#define B_    4
#define HW1   (130*130)
#define HW2   (132*132)
#define NBUF  ((size_t)B_*128*HW2)
#define EPS_  1e-5f
#define PI_   3.14159265358979f

typedef _Float16 half8 __attribute__((ext_vector_type(8)));
typedef _Float16 half4_ __attribute__((ext_vector_type(4)));
typedef float    float4_ __attribute__((ext_vector_type(4)));
typedef float    f32x16 __attribute__((ext_vector_type(16)));

// ============ batched weight pack: fp32 OIHW -> f16 ====
// mode 0 (16x16x32 frags): [cc][tap][g][lane][8], co=g*16+(lane&15), ci=cc*32+(lane>>4)*8+j
// mode 1 (32x32x16 frags): [cc][tap][mt][kh][lane][8], co=mt*32+(lane&31), ci=cc*32+kh*16+(lane>>5)*8+j
struct WPackArgs {
  const float* src[8];
  _Float16*    dst[8];
  int cout[8], cin[8], kk[8], m32[8];
  int off[9];
};
__global__ void wpack_all(WPackArgs p) {
  int idx = blockIdx.x * blockDim.x + threadIdx.x;
  if (idx >= p.off[8]) return;
  int s = 0;
  while (idx >= p.off[s + 1]) ++s;
  int i = idx - p.off[s];
  int Cin = p.cin[s], K = p.kk[s];
  int KK = K * K;
  int j    = i & 7;
  int lane = (i >> 3) & 63;
  int rest = i >> 9;
  int co, ci;
  if (p.m32[s]) {
    int NMT = p.cout[s] / 32;
    int kh  = rest & 1; rest >>= 1;
    int mtg = rest % NMT; rest /= NMT;
    int tap = rest % KK;
    int cc  = rest / KK;
    co = mtg * 32 + (lane & 31);
    ci = cc * 32 + kh * 16 + (lane >> 5) * 8 + j;
    p.dst[s][i] = (_Float16)p.src[s][((size_t)co * Cin + ci) * KK + tap];
  } else {
    int COG = p.cout[s] / 16;
    int g   = rest % COG; rest /= COG;
    int tap = rest % KK;
    int cc  = rest / KK;
    co = g * 16 + (lane & 15);
    ci = cc * 32 + (lane >> 4) * 8 + j;
    p.dst[s][i] = (_Float16)p.src[s][((size_t)co * Cin + ci) * KK + tap];
  }
}

// ============ NCHW f32 -> NHWC f16 (LDS transpose) ============
__global__ void to_nhwc(const float* __restrict__ in, _Float16* __restrict__ out,
                        int C, int HW) {
  __shared__ float t[32][65];
  int b = blockIdx.z, c0 = blockIdx.y * 32, p0 = blockIdx.x * 64;
  int tid = threadIdx.x;
  for (int i = 0; i < 8; ++i) {
    int e = i * 256 + tid; int cl = e >> 6, pl = e & 63;
    int p = p0 + pl;
    float v = 0.f;
    if (p < HW) v = in[((size_t)b * C + c0 + cl) * HW + p];
    t[cl][pl] = v;
  }
  __syncthreads();
  for (int i = 0; i < 8; ++i) {
    int e = i * 256 + tid; int pl = e >> 5, cl = e & 31;
    int p = p0 + pl;
    if (p < HW) out[((size_t)b * HW + p) * C + c0 + cl] = (_Float16)t[cl][pl];
  }
}

__global__ void zerok(float* p, int n) {
  int i = blockIdx.x * blockDim.x + threadIdx.x;
  if (i < n) p[i] = 0.f;
}

// ============ MFMA implicit-GEMM conv ============
// - R1 structure throughout (T14 pipeline, runtime tap-pair loop, recomputed
//   per-tap addresses) — 7 structural variants all regressed; see session log.
// - K>=5: 32x32x16 MFMA, N mapped as 2rows x 16px -> SAME wave tile/grid/LDS as
//   16x16 path, same 4 ds_read + 4 wload per tap, but 8 MFMA instead of 16
//   (m119: 2495 vs 2176 TF pipe rate, half the issue slots).
// - K==3: 16x16x32 path verbatim.
template<int CIN, int COUT, int K, int HIN, int HOUT, bool REFLECT, int AFF, bool RELU, bool POB>
__global__ __launch_bounds__(256, 2) void conv_mfma(
    const _Float16* __restrict__ act, const _Float16* __restrict__ wp,
    const float* __restrict__ sums_in, const float* __restrict__ gam,
    const float* __restrict__ bet, float invn, float* __restrict__ sums_out,
    _Float16* __restrict__ out) {
  constexpr int NWC = (COUT >= 64) ? 2 : 1;
  constexpr int WCO = COUT / NWC;            // 64 / 32 / 32
  constexpr int MR  = WCO / 16;              // 16x16 path M-repeats
  constexpr int MT  = WCO / 32;              // 32x32 path M-tiles (2/1/1)
  constexpr int NMT = COUT / 32;             // total 32-co tiles
  constexpr int NWR = 4 / NWC;
  constexpr int ROWS = NWR * 4;
  constexpr int PADc = (K - 1) / 2;
  constexpr int IR = ROWS + K - 1;
  constexpr int XW = 16 + K - 1;
  constexpr int CH = IR * 4 * XW;            // 16B chunks, idx (row*4+q)*XW+x
  constexpr int COG = COUT / 16;
  constexpr int KK = K * K;
  constexpr int XT = (HOUT + 15) / 16;
  constexpr int NSLAB = CIN / 32;
  constexpr int NST = (CH + 255) / 256;

  __shared__ half8 smem[2][CH];
  __shared__ float2 snorm[CIN];
  __shared__ float bsum[COUT * 2];

  const int xt = blockIdx.x % XT, yt = blockIdx.x / XT;
  const int x0 = xt * 16, y0 = yt * ROWS;
  const int b = blockIdx.z;
  const int tid = threadIdx.x;
  const int lane = tid & 63, w = tid >> 6;
  const int wc = (NWC == 2) ? (w & 1) : 0;
  const int wr = (NWC == 2) ? (w >> 1) : w;
  const int n = lane & 15, q = lane >> 4;

  // ---- preamble: inline norm params + zero block stats ----
  if (AFF) {
    if (tid < CIN) {
      int idx = (AFF == 1 ? b * CIN : 0) + tid;
      float m  = sums_in[idx * 2] * invn;
      float vr = sums_in[idx * 2 + 1] * invn - m * m;
      float sc = rsqrtf(vr + EPS_);
      if (AFF == 2) sc *= gam[tid];
      float sh = (AFF == 2 ? bet[tid] : 0.f) - m * sc;
      snorm[tid] = make_float2(sc, sh);
    }
  }
  if (tid < COUT) { bsum[tid * 2] = 0.f; bsum[tid * 2 + 1] = 0.f; }

  float4_ acc[MR][4];
  f32x16  acc32[MT][2];
  if constexpr (K >= 5) {
#pragma unroll
    for (int mt = 0; mt < MT; ++mt)
#pragma unroll
      for (int rp = 0; rp < 2; ++rp)
#pragma unroll
        for (int j = 0; j < 16; ++j) acc32[mt][rp][j] = 0.f;
  } else {
#pragma unroll
    for (int mi = 0; mi < MR; ++mi)
#pragma unroll
      for (int ni = 0; ni < 4; ++ni)
#pragma unroll
        for (int j = 0; j < 4; ++j) acc[mi][ni][j] = 0.f;
  }

  const _Float16* actb = act + (size_t)b * HIN * HIN * CIN;

  // ---- precompute staging geometry (cc-invariant) ----
  int sidx[NST];
  int soff[NST];
#pragma unroll
  for (int i = 0; i < NST; ++i) {
    int e = tid + i * 256;
    sidx[i] = -1; soff[i] = -1;
    if (e < CH) {
      int qq = e & 3, rx = e >> 2;
      int row = rx / XW, lx = rx % XW;
      int ty = y0 + row - PADc;
      int tx = x0 + lx - PADc;
      bool ok; int iy, ix;
      if (REFLECT) {   // P-space; P = reflect_pad1(x), conv pad=1 zeros outside
        ok = (ty >= 0 && ty < HIN + 2 && tx >= 0 && tx < HIN + 2);
        iy = (ty == 0) ? 1 : (ty == HIN + 1 ? HIN - 2 : ty - 1);
        ix = (tx == 0) ? 1 : (tx == HIN + 1 ? HIN - 2 : tx - 1);
      } else {
        ok = (ty >= 0 && ty < HIN && tx >= 0 && tx < HIN);
        iy = ty; ix = tx;
      }
      sidx[i] = (row * 4 + qq) * XW + lx;
      if (ok) soff[i] = (iy * HIN + ix) * CIN + qq * 8;
    }
  }

  auto ldS = [&](int cc, half8* v) {
#pragma unroll
    for (int i = 0; i < NST; ++i) {
#pragma unroll
      for (int j = 0; j < 8; ++j) v[i][j] = (_Float16)0.f;
      if (soff[i] >= 0) v[i] = *(const half8*)(actb + soff[i] + cc * 32);
    }
  };
  auto wrS = [&](int cc, int buf, half8* v) {
    float nsc[8], nsh[8];
    if (AFF) {
      int cb2 = cc * 32 + (tid & 3) * 8;
#pragma unroll
      for (int j = 0; j < 8; ++j) { float2 t = snorm[cb2 + j]; nsc[j] = t.x; nsh[j] = t.y; }
    }
#pragma unroll
    for (int i = 0; i < NST; ++i) {
      if (sidx[i] >= 0) {
        half8 t = v[i];
        if (AFF && soff[i] >= 0) {
#pragma unroll
          for (int j = 0; j < 8; ++j) {
            float f = (float)t[j] * nsc[j] + nsh[j];
            if (RELU) f = fmaxf(f, 0.f);
            t[j] = (_Float16)f;
          }
        }
        smem[buf][sidx[i]] = t;
      }
    }
  };

  // ---- prologue: stage slab 0 ----
  half8 stg[NST];
  ldS(0, stg);
  __syncthreads();                 // snorm/bsum visible (one-time full drain is fine)
  wrS(0, 0, stg);

  for (int cc = 0; cc < NSLAB; ++cc) {
    const int cur = cc & 1;
    if (cc + 1 < NSLAB) ldS(cc + 1, stg);      // issue next-slab loads EARLY
    asm volatile("s_waitcnt lgkmcnt(0)" ::: "memory");
    __builtin_amdgcn_s_barrier();

    if constexpr (K >= 5) {
      // ---- 32x32x16 path: N = 2rows x 16px; 8 MFMA/tap, same mem-op count ----
      const int dy = q & 1, qh = q >> 1;
      auto ldA = [&](int tap, half8* a) {
#pragma unroll
        for (int mt = 0; mt < MT; ++mt)
#pragma unroll
          for (int kh = 0; kh < 2; ++kh)
            a[mt * 2 + kh] = *(const half8*)(
                wp + ((((size_t)(cc * KK + tap)) * NMT + (wc * MT + mt)) * 2 + kh) * 512
                   + (size_t)lane * 8);
      };
      auto ldB = [&](int tap, half8* c) {
        int ky = tap / K, kx = tap % K;
#pragma unroll
        for (int rp = 0; rp < 2; ++rp)
#pragma unroll
          for (int kh = 0; kh < 2; ++kh)
            c[rp * 2 + kh] =
                smem[cur][((wr * 4 + rp * 2 + dy + ky) * 4 + kh * 2 + qh) * XW + n + kx];
      };
      auto domf = [&](half8* a, half8* c) {
#pragma unroll
        for (int mt = 0; mt < MT; ++mt)
#pragma unroll
          for (int rp = 0; rp < 2; ++rp) {
            acc32[mt][rp] = __builtin_amdgcn_mfma_f32_32x32x16_f16(
                a[mt * 2 + 0], c[rp * 2 + 0], acc32[mt][rp], 0, 0, 0);
            acc32[mt][rp] = __builtin_amdgcn_mfma_f32_32x32x16_f16(
                a[mt * 2 + 1], c[rp * 2 + 1], acc32[mt][rp], 0, 0, 0);
          }
      };
      half8 a0[MT * 2], a1[MT * 2], c0[4], c1[4];
      ldA(0, a0); ldB(0, c0);
      for (int tap = 0; tap + 1 < KK; tap += 2) {   // KK odd: tap+2 <= KK-1 inside
        ldA(tap + 1, a1); ldB(tap + 1, c1);
        domf(a0, c0);
        ldA(tap + 2, a0); ldB(tap + 2, c0);
        domf(a1, c1);
      }
      domf(a0, c0);                                  // tap KK-1
    } else {
      // ---- 16x16x32 path (K==3), R1 verbatim ----
      auto ldA = [&](int tap, half8* a) {
#pragma unroll
        for (int mi = 0; mi < MR; ++mi) {
          int g = wc * MR + mi;
          a[mi] = *(const half8*)(wp + (((size_t)(cc * KK + tap) * COG + g) * 64 + lane) * 8);
        }
      };
      auto ldB = [&](int tap, half8* c) {
        int ky = tap / K, kx = tap % K;
#pragma unroll
        for (int ni = 0; ni < 4; ++ni)
          c[ni] = smem[cur][((wr * 4 + ni + ky) * 4 + q) * XW + n + kx];
      };
      auto domf = [&](half8* a, half8* c) {
#pragma unroll
        for (int mi = 0; mi < MR; ++mi)
#pragma unroll
          for (int ni = 0; ni < 4; ++ni)
            acc[mi][ni] = __builtin_amdgcn_mfma_f32_16x16x32_f16(a[mi], c[ni], acc[mi][ni], 0, 0, 0);
      };
      half8 a0[MR], a1[MR], c0[4], c1[4];
      ldA(0, a0); ldB(0, c0);
      for (int tap = 0; tap + 1 < KK; tap += 2) {
        ldA(tap + 1, a1); ldB(tap + 1, c1);
        domf(a0, c0);
        ldA(tap + 2, a0); ldB(tap + 2, c0);
        domf(a1, c1);
      }
      domf(a0, c0);
    }

    if (cc + 1 < NSLAB) wrS(cc + 1, cur ^ 1, stg); // write-late into other buffer
  }

  _Float16* outb = out + (size_t)b * HOUT * HOUT * COUT;
  const bool xv = (x0 + n) < HOUT;

  if constexpr (K >= 5) {
    // ---- 32x32 epilogue: col=lane&31 -> (dy,x16); co=(reg&3)+8*(reg>>2)+4*qh ----
    const int dy = q & 1, qh = q >> 1;
#pragma unroll
    for (int mt = 0; mt < MT; ++mt) {
#pragma unroll
      for (int g = 0; g < 4; ++g)
#pragma unroll
        for (int jj = 0; jj < 4; ++jj) {
          float s = 0.f, s2 = 0.f;
#pragma unroll
          for (int rp = 0; rp < 2; ++rp) {
            int y = y0 + wr * 4 + rp * 2 + dy;
            float f = acc32[mt][rp][g * 4 + jj];
            bool v = xv && (y < HOUT);
            s  += v ? f : 0.f;
            s2 += v ? f * f : 0.f;
          }
#pragma unroll
          for (int off = 1; off < 32; off <<= 1) {  // reduce over 32 cols
            s  += __shfl_xor(s,  off, 64);
            s2 += __shfl_xor(s2, off, 64);
          }
          if ((lane & 31) == 0) {
            int co = wc * WCO + mt * 32 + g * 8 + qh * 4 + jj;
            atomicAdd(&bsum[co * 2],     s);
            atomicAdd(&bsum[co * 2 + 1], s2);
          }
        }
#pragma unroll
      for (int rp = 0; rp < 2; ++rp) {
        int y = y0 + wr * 4 + rp * 2 + dy, x = x0 + n;
        if (y < HOUT && x < HOUT) {
#pragma unroll
          for (int g = 0; g < 4; ++g) {
            int co = wc * WCO + mt * 32 + g * 8 + qh * 4;
            half4_ h;
#pragma unroll
            for (int jj = 0; jj < 4; ++jj) h[jj] = (_Float16)acc32[mt][rp][g * 4 + jj];
            *(half4_*)(outb + ((size_t)y * HOUT + x) * COUT + co) = h;
          }
        }
      }
    }
  } else {
    // ---- 16x16 epilogue (K==3), R1 verbatim ----
#pragma unroll
    for (int mi = 0; mi < MR; ++mi) {
#pragma unroll
      for (int j = 0; j < 4; ++j) {
        float s = 0.f, s2 = 0.f;
#pragma unroll
        for (int ni = 0; ni < 4; ++ni) {
          int y = y0 + wr * 4 + ni;
          float f = acc[mi][ni][j];
          bool v = xv && (y < HOUT);
          s  += v ? f : 0.f;
          s2 += v ? f * f : 0.f;
        }
#pragma unroll
        for (int off = 1; off < 16; off <<= 1) {
          s  += __shfl_xor(s,  off, 64);
          s2 += __shfl_xor(s2, off, 64);
        }
        if (n == 0) {
          int co = wc * WCO + mi * 16 + q * 4 + j;
          atomicAdd(&bsum[co * 2],     s);
          atomicAdd(&bsum[co * 2 + 1], s2);
        }
      }
    }
#pragma unroll
    for (int mi = 0; mi < MR; ++mi) {
#pragma unroll
      for (int ni = 0; ni < 4; ++ni) {
        int y = y0 + wr * 4 + ni, x = x0 + n;
        if (y < HOUT && x < HOUT) {
          int co = wc * WCO + mi * 16 + q * 4;
          half4_ h;
#pragma unroll
          for (int j = 0; j < 4; ++j) h[j] = (_Float16)acc[mi][ni][j];
          *(half4_*)(outb + ((size_t)y * HOUT + x) * COUT + co) = h;
        }
      }
    }
  }
  __syncthreads();
  if (tid < COUT) {
    int idx = (POB ? b * COUT : 0) + tid;
    atomicAdd(&sums_out[idx * 2],     bsum[tid * 2]);
    atomicAdd(&sums_out[idx * 2 + 1], bsum[tid * 2 + 1]);
  }
}

// ============ analytic DCT-mean weights ============
__global__ void wdctk(float* __restrict__ wd, int N) {
  int i = blockIdx.x * blockDim.x + threadIdx.x;
  if (i >= N) return;
  float Nf = (float)N;
  float c2 = 0.5f * sqrtf(2.f / Nf);
  float a  = sqrtf(1.f / Nf) - c2;
  float phi = PI_ / (4.f * Nf) * (2.f * i + 1.f);
  float cot = cosf(phi) / sinf(phi);
  wd[i] = a + ((i & 1) ? -c2 : c2) * cot;
}

// ============ md[b][c] += sum_p wd[p]*IN(x)  (inline norm from sums2) ============
__global__ void mdctk(const _Float16* __restrict__ x, const float* __restrict__ wd,
                      const float* __restrict__ sums2, float invn,
                      float* __restrict__ md, int HW) {
  int b = blockIdx.z, tid = threadIdx.x;
  int c = tid & 127, pr = tid >> 7;
  int slab = blockIdx.x, nsl = gridDim.x;
  float m  = sums2[(b * 128 + c) * 2] * invn;
  float sc = rsqrtf(sums2[(b * 128 + c) * 2 + 1] * invn - m * m + EPS_);
  float sh = -m * sc;
  const _Float16* xb = x + (size_t)b * HW * 128;
  float s = 0.f;
  for (int p = slab * 2 + pr; p < HW; p += nsl * 2)
    s += ((float)xb[(size_t)p * 128 + c] * sc + sh) * wd[p];
  __shared__ float l1[256];
  l1[tid] = s;
  __syncthreads();
  if (tid < 128) atomicAdd(&md[b * 128 + c], l1[tid] + l1[tid + 128]);
}

// ============ SFOM gate MLP ============
__global__ void gatek(const float* __restrict__ md, const float* __restrict__ w1,
                      const float* __restrict__ w2, float* __restrict__ gate) {
  __shared__ float t1[4][8];
  int tid = threadIdx.x;
  const float invN = 1.f / (float)HW2;
  if (tid < 32) {
    int b = tid >> 3, r = tid & 7;
    float s = 0.f;
    for (int c = 0; c < 128; ++c) s += md[b * 128 + c] * invN * w1[r * 128 + c];
    t1[b][r] = fmaxf(s, 0.f);
  }
  __syncthreads();
  int b = tid >> 7, c = tid & 127;
  float s = 0.f;
#pragma unroll
  for (int r = 0; r < 8; ++r) s += t1[b][r] * w2[c * 8 + r];
  gate[tid] = 1.f / (1.f + expf(-s));
}

// ============ SFOM apply: xn = IN(x); o = sigmoid(xn*(1+g)/2)*xn ============
__global__ void sfomk(const _Float16* __restrict__ x, const float* __restrict__ sums2,
                      float invn, const float* __restrict__ gate,
                      _Float16* __restrict__ o, int HW) {
  size_t idx = (size_t)blockIdx.x * blockDim.x + threadIdx.x;
  size_t tot = (size_t)4 * HW * 16;
  if (idx >= tot) return;
  int cg = (int)(idx % 16);
  size_t bp = idx / 16;
  int b = (int)(bp / HW);
  half8 v = *(const half8*)(x + bp * 128 + cg * 8);
  half8 r;
#pragma unroll
  for (int j = 0; j < 8; ++j) {
    int c = cg * 8 + j;
    float m  = sums2[(b * 128 + c) * 2] * invn;
    float sc = rsqrtf(sums2[(b * 128 + c) * 2 + 1] * invn - m * m + EPS_);
    float f = (float)v[j] * sc - m * sc;
    float g = gate[b * 128 + c];
    float s = 1.f / (1.f + expf(-(f * (1.f + g) * 0.5f)));
    r[j] = (_Float16)(s * f);
  }
  *(half8*)(o + bp * 128 + cg * 8) = r;
}

// ============ sa = sigmoid(b + sum_c cw[c]*relu(BN(h)))  (inline from sums6) ====
__global__ void sak(const _Float16* __restrict__ h, const float* __restrict__ sums6,
                    float invn, const float* __restrict__ gam, const float* __restrict__ bet,
                    const float* __restrict__ cw, const float* __restrict__ cb,
                    float* __restrict__ sa) {
  __shared__ float ssc[32], ssh[32];
  int tid = threadIdx.x;
  if (tid < 32) {
    float m  = sums6[tid * 2] * invn;
    float sc = rsqrtf(sums6[tid * 2 + 1] * invn - m * m + EPS_) * gam[tid];
    ssc[tid] = sc;
    ssh[tid] = bet[tid] - m * sc;
  }
  __syncthreads();
  int idx = blockIdx.x * blockDim.x + tid;
  if (idx >= 4 * HW2) return;
  const _Float16* p = h + (size_t)idx * 32;
  float s = cb[0];
#pragma unroll
  for (int c = 0; c < 32; ++c)
    s += fmaxf((float)p[c] * ssc[c] + ssh[c], 0.f) * cw[c];
  sa[idx] = 1.f / (1.f + expf(-s));
}

// ============ final: NCHW f32 out = sa * O (NHWC f16), LDS transpose ============
__global__ void finalt(const _Float16* __restrict__ o, const float* __restrict__ sa,
                       float* __restrict__ out) {
  __shared__ float t[32][65];
  int b = blockIdx.z, c0 = blockIdx.y * 32, p0 = blockIdx.x * 64;
  int tid = threadIdx.x;
  for (int i = 0; i < 8; ++i) {
    int e = i * 256 + tid; int pl = e >> 5, cl = e & 31;
    int p = p0 + pl;
    if (p < HW2)
      t[cl][pl] = (float)o[((size_t)b * HW2 + p) * 128 + c0 + cl] * sa[b * HW2 + p];
  }
  __syncthreads();
  for (int i = 0; i < 8; ++i) {
    int e = i * 256 + tid; int cl = e >> 6, pl = e & 63;
    int p = p0 + pl;
    if (p < HW2)
      out[((size_t)b * 128 + c0 + cl) * HW2 + p] = t[cl][pl];
  }
}

extern "C" void kernel_launch(void* const* d_in, const int* in_sizes, int n_in,
                              void* d_out, int out_size, void* d_ws, size_t ws_size,
                              hipStream_t stream) {
  const float* x     = (const float*)d_in[0];
  const float* c1w   = (const float*)d_in[1];
  const float* c2w   = (const float*)d_in[3];
  const float* sa_w1 = (const float*)d_in[5];
  const float* sa_w2 = (const float*)d_in[6];
  const float* dw[6] = {(const float*)d_in[7],  (const float*)d_in[10], (const float*)d_in[13],
                        (const float*)d_in[16], (const float*)d_in[19], (const float*)d_in[22]};
  const float* bg[6] = {(const float*)d_in[8],  (const float*)d_in[11], (const float*)d_in[14],
                        (const float*)d_in[17], (const float*)d_in[20], (const float*)d_in[23]};
  const float* bb[6] = {(const float*)d_in[9],  (const float*)d_in[12], (const float*)d_in[15],
                        (const float*)d_in[18], (const float*)d_in[21], (const float*)d_in[24]};
  const float* cw    = (const float*)d_in[25];
  const float* cb    = (const float*)d_in[26];
  float* out = (float*)d_out;

  // ---- workspace carve ----
  char* wsp = (char*)d_ws;
  auto alloc = [&](size_t bytes) { char* p = wsp; wsp += (bytes + 255) & ~(size_t)255; return p; };
  _Float16* B0 = (_Float16*)alloc(NBUF * 2);
  _Float16* B1 = (_Float16*)alloc(NBUF * 2);
  _Float16* B2 = (_Float16*)alloc(NBUF * 2);
  _Float16* B3 = (_Float16*)alloc(NBUF * 2);
  _Float16* wp_c1 = (_Float16*)alloc((size_t)128 * 128 * 9 * 2);
  _Float16* wp_c2 = (_Float16*)alloc((size_t)128 * 128 * 9 * 2);
  const int sci[6] = {128, 32, 64, 128, 128, 64};
  const int sco[6] = {32, 64, 128, 128, 64, 32};
  _Float16* wp_d[6];
  for (int i = 0; i < 6; ++i) wp_d[i] = (_Float16*)alloc((size_t)sco[i] * sci[i] * 49 * 2);
  float* SUMS = (float*)alloc(8704 * 4);     // 8 layer slots x 1024 + md 512
  float* s_c1 = SUMS;
  float* s_c2 = SUMS + 1024;
  float* s_l[6];
  for (int i = 0; i < 6; ++i) s_l[i] = SUMS + 2048 + i * 1024;
  float* md   = SUMS + 8192;
  float* gate = (float*)alloc(512 * 4);
  float* wd   = (float*)alloc((size_t)HW2 * 4);
  float* sa   = (float*)alloc((size_t)4 * HW2 * 4);

  // ---- batched weight pack (ws re-poisoned each call -> redo) ----
  {
    WPackArgs p;
    p.src[0] = c1w; p.dst[0] = wp_c1; p.cout[0] = 128; p.cin[0] = 128; p.kk[0] = 3; p.m32[0] = 0;
    p.src[1] = c2w; p.dst[1] = wp_c2; p.cout[1] = 128; p.cin[1] = 128; p.kk[1] = 3; p.m32[1] = 0;
    for (int i = 0; i < 6; ++i) {
      p.src[2 + i] = dw[i]; p.dst[2 + i] = wp_d[i];
      p.cout[2 + i] = sco[i]; p.cin[2 + i] = sci[i]; p.kk[2 + i] = 7; p.m32[2 + i] = 1;
    }
    p.off[0] = 0;
    for (int i = 0; i < 8; ++i) p.off[i + 1] = p.off[i] + p.cout[i] * p.cin[i] * p.kk[i] * p.kk[i];
    wpack_all<<<(p.off[8] + 255) / 256, 256, 0, stream>>>(p);
  }

  to_nhwc<<<dim3(16384 / 64, 4, 4), 256, 0, stream>>>(x, B0, 128, 16384);
  zerok<<<34, 256, 0, stream>>>(SUMS, 8704);

  const float i1 = 1.f / (float)HW1, i2 = 1.f / (float)HW2, ib = 1.f / (4.f * HW2);

  // conv1: reflect 3x3, no input norm (bias cancels under IN); stats per-(b,c)
  conv_mfma<128, 128, 3, 128, 130, true, 0, false, true><<<dim3(9 * 17, 1, 4), 256, 0, stream>>>(
      B0, wp_c1, nullptr, nullptr, nullptr, 0.f, s_c1, B1);
  // conv2: stages IN(conv1)+relu inline; stats per-(b,c)
  conv_mfma<128, 128, 3, 130, 132, true, 1, true, true><<<dim3(9 * 17, 1, 4), 256, 0, stream>>>(
      B1, wp_c2, s_c1, nullptr, nullptr, i1, s_c2, B2);

  // SFOM (idct(g*dct(x)) == g*x algebraically; mean_k dct = analytic weights)
  wdctk<<<(HW2 + 255) / 256, 256, 0, stream>>>(wd, HW2);
  mdctk<<<dim3(128, 1, 4), 256, 0, stream>>>(B2, wd, s_c2, i2, md, HW2);
  gatek<<<1, 512, 0, stream>>>(md, sa_w1, sa_w2, gate);
  { size_t tot = (size_t)4 * HW2 * 16;
    sfomk<<<(int)((tot + 255) / 256), 256, 0, stream>>>(B2, s_c2, i2, gate, B3, HW2); }

  // SPEM pyramid: 7x7 convs (32x32x16 MFMA path), previous BN+relu staged inline
  conv_mfma<128, 32, 7, 132, 132, false, 0, false, false><<<dim3(9 * 9, 1, 4), 256, 0, stream>>>(
      B3, wp_d[0], nullptr, nullptr, nullptr, 0.f, s_l[0], B0);
  conv_mfma<32, 64, 7, 132, 132, false, 2, true, false><<<dim3(9 * 17, 1, 4), 256, 0, stream>>>(
      B0, wp_d[1], s_l[0], bg[0], bb[0], ib, s_l[1], B1);
  conv_mfma<64, 128, 7, 132, 132, false, 2, true, false><<<dim3(9 * 17, 1, 4), 256, 0, stream>>>(
      B1, wp_d[2], s_l[1], bg[1], bb[1], ib, s_l[2], B0);
  conv_mfma<128, 128, 7, 132, 132, false, 2, true, false><<<dim3(9 * 17, 1, 4), 256, 0, stream>>>(
      B0, wp_d[3], s_l[2], bg[2], bb[2], ib, s_l[3], B1);
  conv_mfma<128, 64, 7, 132, 132, false, 2, true, false><<<dim3(9 * 17, 1, 4), 256, 0, stream>>>(
      B1, wp_d[4], s_l[3], bg[3], bb[3], ib, s_l[4], B0);
  conv_mfma<64, 32, 7, 132, 132, false, 2, true, false><<<dim3(9 * 9, 1, 4), 256, 0, stream>>>(
      B0, wp_d[5], s_l[4], bg[4], bb[4], ib, s_l[5], B1);

  // spatial attention (L6 BN+relu inline) + final product (NCHW f32 out)
  sak<<<(4 * HW2 + 255) / 256, 256, 0, stream>>>(B1, s_l[5], ib, bg[5], bb[5], cw, cb, sa);
  finalt<<<dim3((HW2 + 63) / 64, 4, 4), 256, 0, stream>>>(B3, sa, out);
}

// Round 11
// 733.390 us; speedup vs baseline: 1.0452x; 1.0452x over previous
//
#include <hip/hip_runtime.h>
#include <math.h>

#define B_    4
#define HW1   (130*130)
#define HW2   (132*132)
#define NBUF  ((size_t)B_*128*HW2)
#define EPS_  1e-5f
#define PI_   3.14159265358979f

typedef _Float16 half8 __attribute__((ext_vector_type(8)));
typedef _Float16 half4_ __attribute__((ext_vector_type(4)));
typedef float    float4_ __attribute__((ext_vector_type(4)));

// ============ batched weight pack: fp32 OIHW -> f16 [cc][tap][g][lane][8] ====
// lane=q*16+n ; co=g*16+n ; ci=cc*32+q*8+j  -> A-frag load is 1KB wave-contiguous
struct WPackArgs {
  const float* src[8];
  _Float16*    dst[8];
  int cout[8], cin[8], kk[8];
  int off[9];
};
__global__ void wpack_all(WPackArgs p) {
  int idx = blockIdx.x * blockDim.x + threadIdx.x;
  if (idx >= p.off[8]) return;
  int s = 0;
  while (idx >= p.off[s + 1]) ++s;
  int i = idx - p.off[s];
  int Cin = p.cin[s], K = p.kk[s];
  int KK = K * K, COG = p.cout[s] / 16;
  int j    = i & 7;
  int lane = (i >> 3) & 63;
  int rest = i >> 9;
  int g    = rest % COG; rest /= COG;
  int tap  = rest % KK;
  int cc   = rest / KK;
  int n = lane & 15, q = lane >> 4;
  int co = g * 16 + n;
  int ci = cc * 32 + q * 8 + j;
  p.dst[s][i] = (_Float16)p.src[s][((size_t)co * Cin + ci) * KK + tap];
}

// ============ NCHW f32 -> NHWC f16 (LDS transpose) ============
__global__ void to_nhwc(const float* __restrict__ in, _Float16* __restrict__ out,
                        int C, int HW) {
  __shared__ float t[32][65];
  int b = blockIdx.z, c0 = blockIdx.y * 32, p0 = blockIdx.x * 64;
  int tid = threadIdx.x;
  for (int i = 0; i < 8; ++i) {
    int e = i * 256 + tid; int cl = e >> 6, pl = e & 63;
    int p = p0 + pl;
    float v = 0.f;
    if (p < HW) v = in[((size_t)b * C + c0 + cl) * HW + p];
    t[cl][pl] = v;
  }
  __syncthreads();
  for (int i = 0; i < 8; ++i) {
    int e = i * 256 + tid; int pl = e >> 5, cl = e & 31;
    int p = p0 + pl;
    if (p < HW) out[((size_t)b * HW + p) * C + c0 + cl] = (_Float16)t[cl][pl];
  }
}

__global__ void zerok(float* p, int n) {
  int i = blockIdx.x * blockDim.x + threadIdx.x;
  if (i < n) p[i] = 0.f;
}

// ============ MFMA implicit-GEMM conv ============
// - R1 structure (T14 pipeline, runtime tap-pair loop, recomputed per-tap
//   addresses): 8 structural variants + 32x32 MFMA swap all regressed.
// - ONLY change vs the verified 734.8us baseline: __launch_bounds__(256,3).
//   Grids are 612/324 blocks; at 2 blocks/CU only 512 slots exist -> ~20-25%
//   dispatch tail (100 CUs run a 3rd block nearly alone). At 3 blocks/CU
//   (LDS 41.5KB*3=124KB<160KB, VGPR 84<168) every grid is fully co-resident:
//   no tail + 12 waves/CU of TLP to overlap MFMA/LDS/VALU pipes.
template<int CIN, int COUT, int K, int HIN, int HOUT, bool REFLECT, int AFF, bool RELU, bool POB>
__global__ __launch_bounds__(256, 3) void conv_mfma(
    const _Float16* __restrict__ act, const _Float16* __restrict__ wp,
    const float* __restrict__ sums_in, const float* __restrict__ gam,
    const float* __restrict__ bet, float invn, float* __restrict__ sums_out,
    _Float16* __restrict__ out) {
  constexpr int NWC = (COUT >= 64) ? 2 : 1;
  constexpr int WCO = COUT / NWC;            // 64 / 32 / 32
  constexpr int MR  = WCO / 16;              // 4 / 2 / 2
  constexpr int NWR = 4 / NWC;               // 2 / 2 / 4
  constexpr int ROWS = NWR * 4;              // 8 / 8 / 16
  constexpr int PADc = (K - 1) / 2;
  constexpr int IR = ROWS + K - 1;
  constexpr int XW = 16 + K - 1;
  constexpr int CH = IR * 4 * XW;            // 16B chunks, idx (row*4+q)*XW+x
  constexpr int COG = COUT / 16;
  constexpr int KK = K * K;
  constexpr int XT = (HOUT + 15) / 16;
  constexpr int NSLAB = CIN / 32;
  constexpr int NST = (CH + 255) / 256;      // staging chunks per thread

  __shared__ half8 smem[2][CH];
  __shared__ float2 snorm[CIN];
  __shared__ float bsum[COUT * 2];

  const int xt = blockIdx.x % XT, yt = blockIdx.x / XT;
  const int x0 = xt * 16, y0 = yt * ROWS;
  const int b = blockIdx.z;
  const int tid = threadIdx.x;
  const int lane = tid & 63, w = tid >> 6;
  const int wc = (NWC == 2) ? (w & 1) : 0;
  const int wr = (NWC == 2) ? (w >> 1) : w;
  const int n = lane & 15, q = lane >> 4;

  // ---- preamble: inline norm params + zero block stats ----
  if (AFF) {
    if (tid < CIN) {
      int idx = (AFF == 1 ? b * CIN : 0) + tid;
      float m  = sums_in[idx * 2] * invn;
      float vr = sums_in[idx * 2 + 1] * invn - m * m;
      float sc = rsqrtf(vr + EPS_);
      if (AFF == 2) sc *= gam[tid];
      float sh = (AFF == 2 ? bet[tid] : 0.f) - m * sc;
      snorm[tid] = make_float2(sc, sh);
    }
  }
  if (tid < COUT) { bsum[tid * 2] = 0.f; bsum[tid * 2 + 1] = 0.f; }

  float4_ acc[MR][4];
#pragma unroll
  for (int mi = 0; mi < MR; ++mi)
#pragma unroll
    for (int ni = 0; ni < 4; ++ni)
#pragma unroll
      for (int j = 0; j < 4; ++j) acc[mi][ni][j] = 0.f;

  const _Float16* actb = act + (size_t)b * HIN * HIN * CIN;

  // ---- precompute staging geometry (cc-invariant) ----
  int sidx[NST];   // LDS chunk index, -1 = no element (tail)
  int soff[NST];   // global half-elem offset (sans cc*32), -1 = out-of-bounds (zero)
#pragma unroll
  for (int i = 0; i < NST; ++i) {
    int e = tid + i * 256;
    sidx[i] = -1; soff[i] = -1;
    if (e < CH) {
      int qq = e & 3, rx = e >> 2;
      int row = rx / XW, lx = rx % XW;
      int ty = y0 + row - PADc;
      int tx = x0 + lx - PADc;
      bool ok; int iy, ix;
      if (REFLECT) {   // P-space; P = reflect_pad1(x), conv pad=1 zeros outside
        ok = (ty >= 0 && ty < HIN + 2 && tx >= 0 && tx < HIN + 2);
        iy = (ty == 0) ? 1 : (ty == HIN + 1 ? HIN - 2 : ty - 1);
        ix = (tx == 0) ? 1 : (tx == HIN + 1 ? HIN - 2 : tx - 1);
      } else {
        ok = (ty >= 0 && ty < HIN && tx >= 0 && tx < HIN);
        iy = ty; ix = tx;
      }
      sidx[i] = (row * 4 + qq) * XW + lx;
      if (ok) soff[i] = (iy * HIN + ix) * CIN + qq * 8;
    }
  }

  auto ldS = [&](int cc, half8* v) {
#pragma unroll
    for (int i = 0; i < NST; ++i) {
#pragma unroll
      for (int j = 0; j < 8; ++j) v[i][j] = (_Float16)0.f;
      if (soff[i] >= 0) v[i] = *(const half8*)(actb + soff[i] + cc * 32);
    }
  };
  auto wrS = [&](int cc, int buf, half8* v) {
    float nsc[8], nsh[8];
    if (AFF) {
      int cb2 = cc * 32 + (tid & 3) * 8;
#pragma unroll
      for (int j = 0; j < 8; ++j) { float2 t = snorm[cb2 + j]; nsc[j] = t.x; nsh[j] = t.y; }
    }
#pragma unroll
    for (int i = 0; i < NST; ++i) {
      if (sidx[i] >= 0) {
        half8 t = v[i];
        if (AFF && soff[i] >= 0) {
#pragma unroll
          for (int j = 0; j < 8; ++j) {
            float f = (float)t[j] * nsc[j] + nsh[j];
            if (RELU) f = fmaxf(f, 0.f);
            t[j] = (_Float16)f;
          }
        }
        smem[buf][sidx[i]] = t;
      }
    }
  };

  // ---- prologue: stage slab 0 ----
  half8 stg[NST];
  ldS(0, stg);
  __syncthreads();                 // snorm/bsum visible (one-time full drain is fine)
  wrS(0, 0, stg);

  for (int cc = 0; cc < NSLAB; ++cc) {
    const int cur = cc & 1;
    if (cc + 1 < NSLAB) ldS(cc + 1, stg);      // issue next-slab loads EARLY
    // own ds_writes (prev wrS) must land before signaling; do NOT drain vmcnt
    asm volatile("s_waitcnt lgkmcnt(0)" ::: "memory");
    __builtin_amdgcn_s_barrier();

    // ---- compute: taps double-buffered (prefetch A from global, B from LDS) ----
    auto ldA = [&](int tap, half8* a) {
#pragma unroll
      for (int mi = 0; mi < MR; ++mi) {
        int g = wc * MR + mi;
        a[mi] = *(const half8*)(wp + (((size_t)(cc * KK + tap) * COG + g) * 64 + lane) * 8);
      }
    };
    auto ldB = [&](int tap, half8* c) {
      int ky = tap / K, kx = tap % K;
#pragma unroll
      for (int ni = 0; ni < 4; ++ni)
        c[ni] = smem[cur][((wr * 4 + ni + ky) * 4 + q) * XW + n + kx];
    };
    auto domf = [&](half8* a, half8* c) {
#pragma unroll
      for (int mi = 0; mi < MR; ++mi)
#pragma unroll
        for (int ni = 0; ni < 4; ++ni)
          acc[mi][ni] = __builtin_amdgcn_mfma_f32_16x16x32_f16(a[mi], c[ni], acc[mi][ni], 0, 0, 0);
    };
    half8 a0[MR], a1[MR], c0[4], c1[4];
    ldA(0, a0); ldB(0, c0);
    for (int tap = 0; tap + 1 < KK; tap += 2) {   // KK odd: tap+2 <= KK-1 inside
      ldA(tap + 1, a1); ldB(tap + 1, c1);
      domf(a0, c0);
      ldA(tap + 2, a0); ldB(tap + 2, c0);
      domf(a1, c1);
    }
    domf(a0, c0);                                  // tap KK-1

    if (cc + 1 < NSLAB) wrS(cc + 1, cur ^ 1, stg); // write-late into other buffer
  }

  // ---- epilogue 1: per-co stats from f32 accumulators ----
  const bool xv = (x0 + n) < HOUT;
#pragma unroll
  for (int mi = 0; mi < MR; ++mi) {
#pragma unroll
    for (int j = 0; j < 4; ++j) {
      float s = 0.f, s2 = 0.f;
#pragma unroll
      for (int ni = 0; ni < 4; ++ni) {
        int y = y0 + wr * 4 + ni;
        float f = acc[mi][ni][j];
        bool v = xv && (y < HOUT);
        s  += v ? f : 0.f;
        s2 += v ? f * f : 0.f;
      }
#pragma unroll
      for (int off = 1; off < 16; off <<= 1) {    // reduce across the 16 n-lanes
        s  += __shfl_xor(s,  off, 64);
        s2 += __shfl_xor(s2, off, 64);
      }
      if (n == 0) {
        int co = wc * WCO + mi * 16 + q * 4 + j;
        atomicAdd(&bsum[co * 2],     s);
        atomicAdd(&bsum[co * 2 + 1], s2);
      }
    }
  }
  // ---- epilogue 2: store NHWC f16 (raw conv out; norm applied by consumer) ----
  _Float16* outb = out + (size_t)b * HOUT * HOUT * COUT;
#pragma unroll
  for (int mi = 0; mi < MR; ++mi) {
#pragma unroll
    for (int ni = 0; ni < 4; ++ni) {
      int y = y0 + wr * 4 + ni, x = x0 + n;
      if (y < HOUT && x < HOUT) {
        int co = wc * WCO + mi * 16 + q * 4;
        half4_ h;
#pragma unroll
        for (int j = 0; j < 4; ++j) h[j] = (_Float16)acc[mi][ni][j];
        *(half4_*)(outb + ((size_t)y * HOUT + x) * COUT + co) = h;
      }
    }
  }
  __syncthreads();
  if (tid < COUT) {
    int idx = (POB ? b * COUT : 0) + tid;
    atomicAdd(&sums_out[idx * 2],     bsum[tid * 2]);
    atomicAdd(&sums_out[idx * 2 + 1], bsum[tid * 2 + 1]);
  }
}

// ============ analytic DCT-mean weights ============
__global__ void wdctk(float* __restrict__ wd, int N) {
  int i = blockIdx.x * blockDim.x + threadIdx.x;
  if (i >= N) return;
  float Nf = (float)N;
  float c2 = 0.5f * sqrtf(2.f / Nf);
  float a  = sqrtf(1.f / Nf) - c2;
  float phi = PI_ / (4.f * Nf) * (2.f * i + 1.f);
  float cot = cosf(phi) / sinf(phi);
  wd[i] = a + ((i & 1) ? -c2 : c2) * cot;
}

// ============ md[b][c] += sum_p wd[p]*IN(x)  (inline norm from sums2) ============
__global__ void mdctk(const _Float16* __restrict__ x, const float* __restrict__ wd,
                      const float* __restrict__ sums2, float invn,
                      float* __restrict__ md, int HW) {
  int b = blockIdx.z, tid = threadIdx.x;
  int c = tid & 127, pr = tid >> 7;
  int slab = blockIdx.x, nsl = gridDim.x;
  float m  = sums2[(b * 128 + c) * 2] * invn;
  float sc = rsqrtf(sums2[(b * 128 + c) * 2 + 1] * invn - m * m + EPS_);
  float sh = -m * sc;
  const _Float16* xb = x + (size_t)b * HW * 128;
  float s = 0.f;
  for (int p = slab * 2 + pr; p < HW; p += nsl * 2)
    s += ((float)xb[(size_t)p * 128 + c] * sc + sh) * wd[p];
  __shared__ float l1[256];
  l1[tid] = s;
  __syncthreads();
  if (tid < 128) atomicAdd(&md[b * 128 + c], l1[tid] + l1[tid + 128]);
}

// ============ SFOM gate MLP ============
__global__ void gatek(const float* __restrict__ md, const float* __restrict__ w1,
                      const float* __restrict__ w2, float* __restrict__ gate) {
  __shared__ float t1[4][8];
  int tid = threadIdx.x;
  const float invN = 1.f / (float)HW2;
  if (tid < 32) {
    int b = tid >> 3, r = tid & 7;
    float s = 0.f;
    for (int c = 0; c < 128; ++c) s += md[b * 128 + c] * invN * w1[r * 128 + c];
    t1[b][r] = fmaxf(s, 0.f);
  }
  __syncthreads();
  int b = tid >> 7, c = tid & 127;
  float s = 0.f;
#pragma unroll
  for (int r = 0; r < 8; ++r) s += t1[b][r] * w2[c * 8 + r];
  gate[tid] = 1.f / (1.f + expf(-s));
}

// ============ SFOM apply: xn = IN(x); o = sigmoid(xn*(1+g)/2)*xn ============
__global__ void sfomk(const _Float16* __restrict__ x, const float* __restrict__ sums2,
                      float invn, const float* __restrict__ gate,
                      _Float16* __restrict__ o, int HW) {
  size_t idx = (size_t)blockIdx.x * blockDim.x + threadIdx.x;
  size_t tot = (size_t)4 * HW * 16;
  if (idx >= tot) return;
  int cg = (int)(idx % 16);
  size_t bp = idx / 16;
  int b = (int)(bp / HW);
  half8 v = *(const half8*)(x + bp * 128 + cg * 8);
  half8 r;
#pragma unroll
  for (int j = 0; j < 8; ++j) {
    int c = cg * 8 + j;
    float m  = sums2[(b * 128 + c) * 2] * invn;
    float sc = rsqrtf(sums2[(b * 128 + c) * 2 + 1] * invn - m * m + EPS_);
    float f = (float)v[j] * sc - m * sc;
    float g = gate[b * 128 + c];
    float s = 1.f / (1.f + expf(-(f * (1.f + g) * 0.5f)));
    r[j] = (_Float16)(s * f);
  }
  *(half8*)(o + bp * 128 + cg * 8) = r;
}

// ============ sa = sigmoid(b + sum_c cw[c]*relu(BN(h)))  (inline from sums6) ====
__global__ void sak(const _Float16* __restrict__ h, const float* __restrict__ sums6,
                    float invn, const float* __restrict__ gam, const float* __restrict__ bet,
                    const float* __restrict__ cw, const float* __restrict__ cb,
                    float* __restrict__ sa) {
  __shared__ float ssc[32], ssh[32];
  int tid = threadIdx.x;
  if (tid < 32) {
    float m  = sums6[tid * 2] * invn;
    float sc = rsqrtf(sums6[tid * 2 + 1] * invn - m * m + EPS_) * gam[tid];
    ssc[tid] = sc;
    ssh[tid] = bet[tid] - m * sc;
  }
  __syncthreads();
  int idx = blockIdx.x * blockDim.x + tid;
  if (idx >= 4 * HW2) return;
  const _Float16* p = h + (size_t)idx * 32;
  float s = cb[0];
#pragma unroll
  for (int c = 0; c < 32; ++c)
    s += fmaxf((float)p[c] * ssc[c] + ssh[c], 0.f) * cw[c];
  sa[idx] = 1.f / (1.f + expf(-s));
}

// ============ final: NCHW f32 out = sa * O (NHWC f16), LDS transpose ============
__global__ void finalt(const _Float16* __restrict__ o, const float* __restrict__ sa,
                       float* __restrict__ out) {
  __shared__ float t[32][65];
  int b = blockIdx.z, c0 = blockIdx.y * 32, p0 = blockIdx.x * 64;
  int tid = threadIdx.x;
  for (int i = 0; i < 8; ++i) {
    int e = i * 256 + tid; int pl = e >> 5, cl = e & 31;
    int p = p0 + pl;
    if (p < HW2)
      t[cl][pl] = (float)o[((size_t)b * HW2 + p) * 128 + c0 + cl] * sa[b * HW2 + p];
  }
  __syncthreads();
  for (int i = 0; i < 8; ++i) {
    int e = i * 256 + tid; int cl = e >> 6, pl = e & 63;
    int p = p0 + pl;
    if (p < HW2)
      out[((size_t)b * 128 + c0 + cl) * HW2 + p] = t[cl][pl];
  }
}

extern "C" void kernel_launch(void* const* d_in, const int* in_sizes, int n_in,
                              void* d_out, int out_size, void* d_ws, size_t ws_size,
                              hipStream_t stream) {
  const float* x     = (const float*)d_in[0];
  const float* c1w   = (const float*)d_in[1];
  const float* c2w   = (const float*)d_in[3];
  const float* sa_w1 = (const float*)d_in[5];
  const float* sa_w2 = (const float*)d_in[6];
  const float* dw[6] = {(const float*)d_in[7],  (const float*)d_in[10], (const float*)d_in[13],
                        (const float*)d_in[16], (const float*)d_in[19], (const float*)d_in[22]};
  const float* bg[6] = {(const float*)d_in[8],  (const float*)d_in[11], (const float*)d_in[14],
                        (const float*)d_in[17], (const float*)d_in[20], (const float*)d_in[23]};
  const float* bb[6] = {(const float*)d_in[9],  (const float*)d_in[12], (const float*)d_in[15],
                        (const float*)d_in[18], (const float*)d_in[21], (const float*)d_in[24]};
  const float* cw    = (const float*)d_in[25];
  const float* cb    = (const float*)d_in[26];
  float* out = (float*)d_out;

  // ---- workspace carve ----
  char* wsp = (char*)d_ws;
  auto alloc = [&](size_t bytes) { char* p = wsp; wsp += (bytes + 255) & ~(size_t)255; return p; };
  _Float16* B0 = (_Float16*)alloc(NBUF * 2);
  _Float16* B1 = (_Float16*)alloc(NBUF * 2);
  _Float16* B2 = (_Float16*)alloc(NBUF * 2);
  _Float16* B3 = (_Float16*)alloc(NBUF * 2);
  _Float16* wp_c1 = (_Float16*)alloc((size_t)128 * 128 * 9 * 2);
  _Float16* wp_c2 = (_Float16*)alloc((size_t)128 * 128 * 9 * 2);
  const int sci[6] = {128, 32, 64, 128, 128, 64};
  const int sco[6] = {32, 64, 128, 128, 64, 32};
  _Float16* wp_d[6];
  for (int i = 0; i < 6; ++i) wp_d[i] = (_Float16*)alloc((size_t)sco[i] * sci[i] * 49 * 2);
  float* SUMS = (float*)alloc(8704 * 4);     // 8 layer slots x 1024 + md 512
  float* s_c1 = SUMS;
  float* s_c2 = SUMS + 1024;
  float* s_l[6];
  for (int i = 0; i < 6; ++i) s_l[i] = SUMS + 2048 + i * 1024;
  float* md   = SUMS + 8192;
  float* gate = (float*)alloc(512 * 4);
  float* wd   = (float*)alloc((size_t)HW2 * 4);
  float* sa   = (float*)alloc((size_t)4 * HW2 * 4);

  // ---- batched weight pack (ws re-poisoned each call -> redo) ----
  {
    WPackArgs p;
    p.src[0] = c1w; p.dst[0] = wp_c1; p.cout[0] = 128; p.cin[0] = 128; p.kk[0] = 3;
    p.src[1] = c2w; p.dst[1] = wp_c2; p.cout[1] = 128; p.cin[1] = 128; p.kk[1] = 3;
    for (int i = 0; i < 6; ++i) {
      p.src[2 + i] = dw[i]; p.dst[2 + i] = wp_d[i];
      p.cout[2 + i] = sco[i]; p.cin[2 + i] = sci[i]; p.kk[2 + i] = 7;
    }
    p.off[0] = 0;
    for (int i = 0; i < 8; ++i) p.off[i + 1] = p.off[i] + p.cout[i] * p.cin[i] * p.kk[i] * p.kk[i];
    wpack_all<<<(p.off[8] + 255) / 256, 256, 0, stream>>>(p);
  }

  to_nhwc<<<dim3(16384 / 64, 4, 4), 256, 0, stream>>>(x, B0, 128, 16384);
  zerok<<<34, 256, 0, stream>>>(SUMS, 8704);

  const float i1 = 1.f / (float)HW1, i2 = 1.f / (float)HW2, ib = 1.f / (4.f * HW2);

  // conv1: reflect 3x3, no input norm (bias cancels under IN); stats per-(b,c)
  conv_mfma<128, 128, 3, 128, 130, true, 0, false, true><<<dim3(9 * 17, 1, 4), 256, 0, stream>>>(
      B0, wp_c1, nullptr, nullptr, nullptr, 0.f, s_c1, B1);
  // conv2: stages IN(conv1)+relu inline; stats per-(b,c)
  conv_mfma<128, 128, 3, 130, 132, true, 1, true, true><<<dim3(9 * 17, 1, 4), 256, 0, stream>>>(
      B1, wp_c2, s_c1, nullptr, nullptr, i1, s_c2, B2);

  // SFOM (idct(g*dct(x)) == g*x algebraically; mean_k dct = analytic weights)
  wdctk<<<(HW2 + 255) / 256, 256, 0, stream>>>(wd, HW2);
  mdctk<<<dim3(128, 1, 4), 256, 0, stream>>>(B2, wd, s_c2, i2, md, HW2);
  gatek<<<1, 512, 0, stream>>>(md, sa_w1, sa_w2, gate);
  { size_t tot = (size_t)4 * HW2 * 16;
    sfomk<<<(int)((tot + 255) / 256), 256, 0, stream>>>(B2, s_c2, i2, gate, B3, HW2); }

  // SPEM pyramid: 7x7 convs, each staging applies previous BN+relu inline
  conv_mfma<128, 32, 7, 132, 132, false, 0, false, false><<<dim3(9 * 9, 1, 4), 256, 0, stream>>>(
      B3, wp_d[0], nullptr, nullptr, nullptr, 0.f, s_l[0], B0);
  conv_mfma<32, 64, 7, 132, 132, false, 2, true, false><<<dim3(9 * 17, 1, 4), 256, 0, stream>>>(
      B0, wp_d[1], s_l[0], bg[0], bb[0], ib, s_l[1], B1);
  conv_mfma<64, 128, 7, 132, 132, false, 2, true, false><<<dim3(9 * 17, 1, 4), 256, 0, stream>>>(
      B1, wp_d[2], s_l[1], bg[1], bb[1], ib, s_l[2], B0);
  conv_mfma<128, 128, 7, 132, 132, false, 2, true, false><<<dim3(9 * 17, 1, 4), 256, 0, stream>>>(
      B0, wp_d[3], s_l[2], bg[2], bb[2], ib, s_l[3], B1);
  conv_mfma<128, 64, 7, 132, 132, false, 2, true, false><<<dim3(9 * 17, 1, 4), 256, 0, stream>>>(
      B1, wp_d[4], s_l[3], bg[3], bb[3], ib, s_l[4], B0);
  conv_mfma<64, 32, 7, 132, 132, false, 2, true, false><<<dim3(9 * 9, 1, 4), 256, 0, stream>>>(
      B0, wp_d[5], s_l[4], bg[4], bb[4], ib, s_l[5], B1);

  // spatial attention (L6 BN+relu inline) + final product (NCHW f32 out)
  sak<<<(4 * HW2 + 255) / 256, 256, 0, stream>>>(B1, s_l[5], ib, bg[5], bb[5], cw, cb, sa);
  finalt<<<dim3((HW2 + 63) / 64, 4, 4), 256, 0, stream>>>(B3, sa, out);
}